// Round 11
// baseline (126.064 us; speedup 1.0000x reference)
//
#include <hip/hip_runtime.h>
#include <math.h>

// MatchingLayer (BiMPM-style) — MI355X. Round 11: SINGLE dispatch (k_prep
// folded into k_main; every block self-stages from ctx), Dscr stride 9
// (bank-conflict fix). Grid (20+32, B) x 512 thr. B=32,L=128,H=100,P=20,C=105.

namespace {
constexpr int B = 32;
constexpr int L = 128;
constexpr int H = 100;
constexpr int P = 20;
constexpr int C = 105;
constexpr int TI = 8;            // i-rows per side tile
constexpr int SMEM_BYTES = 50176;
constexpr float EPSF = 1e-8f;
constexpr float MINV = -1e7f;
}

typedef unsigned short u16;
typedef unsigned int u32;
typedef short sh8 __attribute__((ext_vector_type(8)));   // 8 bf16 (4 VGPRs)
typedef float f4 __attribute__((ext_vector_type(4)));

__device__ __forceinline__ u16 f2bf(float f) {           // RNE f32->bf16
    u32 u = __float_as_uint(f);
    u += 0x7FFFu + ((u >> 16) & 1u);
    return (u16)(u >> 16);
}
__device__ __forceinline__ u32 pack2(float a, float b) {
    return (u32)f2bf(a) | ((u32)f2bf(b) << 16);
}
// pack 8 fp32 (scaled) -> uint4 of bf16
__device__ __forceinline__ uint4 pack8(const float4 h0, const float4 h1) {
    uint4 o;
    o.x = pack2(h0.x, h0.y); o.y = pack2(h0.z, h0.w);
    o.z = pack2(h1.x, h1.y); o.w = pack2(h1.z, h1.w);
    return o;
}
__device__ __forceinline__ float4 zero4() { return (float4){0.f, 0.f, 0.f, 0.f}; }

// ---------------------------------------------------------------- k_main
__global__ __launch_bounds__(512) void
k_main(const float* __restrict__ ctx_p, const int* __restrict__ mask_p,
       const float* __restrict__ ctx_h, const int* __restrict__ mask_h,
       const float* __restrict__ w0, const float* __restrict__ w1,
       const float* __restrict__ w2, const float* __restrict__ w3,
       float* __restrict__ out)
{
    __shared__ __align__(16) char smem[SMEM_BYTES];
    const int bx = blockIdx.x, b = blockIdx.y, t = threadIdx.x;
    const int wv = t >> 6, ln = t & 63;
    float* out_p = out;
    float* out_h = out + (size_t)B * L * C;

    if (bx < P) {
        // ==================== pair path ====================
        // LDS: sB u16[128][136] @0; snwA@34816 snwB@35328 smA@35840 smB@36352
        //      pJmax@36864 pJsum@37376 pImax[8][128]@37888 pIsum@41984
        //      sRed@46080 sw1sq[128]@46096
        const int p = bx;
        u16*  sB    = (u16*)smem;
        float* snwA = (float*)(smem + 34816);
        float* snwB = (float*)(smem + 35328);
        float* smA  = (float*)(smem + 35840);
        float* smB  = (float*)(smem + 36352);
        float* pJmax= (float*)(smem + 36864);
        float* pJsum= (float*)(smem + 37376);
        float* pImax= (float*)(smem + 37888);
        float* pIsum= (float*)(smem + 41984);
        float* sRed = (float*)(smem + 46080);
        float* sw1sq= (float*)(smem + 46096);

        // phase (i): masks + w1^2 row
        if (t < 128) smA[t] = (float)mask_p[b * L + t];
        else if (t < 256) smB[t - 128] = (float)mask_h[b * L + (t - 128)];
        else if (t < 384) {
            int k = t - 256;
            float w = (k < H) ? w1[p * H + k] : 0.f;
            sw1sq[k] = w * w;
        }
        __syncthreads();

        // phase (ii): t<256 -> weighted norms (1 row each, both sides);
        //             t>=256 -> stage B tile (ctx_h fp32 -> bf16, stride 136)
        if (t < 256) {
            const int sideSel = t >> 7, rr = t & 127;
            const float* rowp = (sideSel ? ctx_h : ctx_p) + ((size_t)b * L + rr) * H;
            const float mrow = sideSel ? smB[rr] : smA[rr];
            const float4* r4 = (const float4*)rowp;
            float acc = 0.f;
            #pragma unroll 5
            for (int k4 = 0; k4 < 25; ++k4) {
                float4 v = r4[k4];
                const float* wq = sw1sq + k4 * 4;
                float v0 = v.x * mrow, v1 = v.y * mrow, v2 = v.z * mrow, v3 = v.w * mrow;
                acc += wq[0] * v0 * v0 + wq[1] * v1 * v1 +
                       wq[2] * v2 * v2 + wq[3] * v3 * v3;
            }
            (sideSel ? snwB : snwA)[rr] = sqrtf(acc);
        } else {
            for (int idx = t - 256; idx < 2048; idx += 256) {
                int row = idx >> 4, c = idx & 15, k0 = c * 8;
                const float* rowp = ctx_h + ((size_t)b * L + row) * H;
                float mrow = smB[row];
                float4 h0 = (k0 <= 96) ? *(const float4*)(rowp + k0) : zero4();
                float4 h1 = (k0 + 4 <= 96) ? *(const float4*)(rowp + k0 + 4) : zero4();
                h0.x *= mrow; h0.y *= mrow; h0.z *= mrow; h0.w *= mrow;
                h1.x *= mrow; h1.y *= mrow; h1.z *= mrow; h1.w *= mrow;
                *(uint4*)&sB[row * 136 + k0] = pack8(h0, h1);
            }
        }
        // sRed from masks (threads <128 already finished their norm row)
        if (t < 64) {
            float a0 = smB[t], a1 = smB[t + 64];
            float mx = fmaxf(a0, a1), sm = a0 + a1;
            for (int d = 1; d < 64; d <<= 1) {
                mx = fmaxf(mx, __shfl_xor(mx, d));
                sm += __shfl_xor(sm, d);
            }
            if (t == 0) { sRed[2] = mx; sRed[3] = sm; }
        } else if (t < 128) {
            const int l = t - 64;
            float a0 = smA[l], a1 = smA[l + 64];
            float mx = fmaxf(a0, a1), sm = a0 + a1;
            for (int d = 1; d < 64; d <<= 1) {
                mx = fmaxf(mx, __shfl_xor(mx, d));
                sm += __shfl_xor(sm, d);
            }
            if (l == 0) { sRed[0] = mx; sRed[1] = sm; }
        }
        __syncthreads();

        const int m = ln & 15, q = ln >> 4;

        float swv[4][8];
        #pragma unroll
        for (int ks = 0; ks < 4; ++ks)
            #pragma unroll
            for (int e = 0; e < 8; ++e) {
                int k = ks * 32 + q * 8 + e;
                swv[ks][e] = (k < H) ? sw1sq[k] : 0.f;
            }

        f4 acc[8];
        #pragma unroll
        for (int ct = 0; ct < 8; ++ct) acc[ct] = (f4){0.f, 0.f, 0.f, 0.f};

        {
            const int arow = wv * 16 + m;
            const float* rowp = ctx_p + ((size_t)b * L + arow) * H;
            const float mA = smA[arow];
            #pragma unroll
            for (int ks = 0; ks < 4; ++ks) {
                const int k0 = ks * 32 + q * 8;
                float4 h0 = (k0 <= 96) ? *(const float4*)(rowp + k0) : zero4();
                float4 h1 = (k0 + 4 <= 96) ? *(const float4*)(rowp + k0 + 4) : zero4();
                sh8 af;
                {
                    uint4 o;
                    o.x = pack2(h0.x * mA * swv[ks][0], h0.y * mA * swv[ks][1]);
                    o.y = pack2(h0.z * mA * swv[ks][2], h0.w * mA * swv[ks][3]);
                    o.z = pack2(h1.x * mA * swv[ks][4], h1.y * mA * swv[ks][5]);
                    o.w = pack2(h1.z * mA * swv[ks][6], h1.w * mA * swv[ks][7]);
                    af = __builtin_bit_cast(sh8, o);
                }
                const int ko = ks * 32 + q * 8;
                #pragma unroll
                for (int ct = 0; ct < 8; ++ct) {
                    sh8 bb = *(const sh8*)&sB[(ct * 16 + m) * 136 + ko];
                    acc[ct] = __builtin_amdgcn_mfma_f32_16x16x32_bf16(af, bb, acc[ct], 0, 0, 0);
                }
            }
        }

        // epilogue: mv = acc / max(nwA*nwB, eps); pool over j and i
        float nB[8], mBv[8], imax[8], isum[8];
        #pragma unroll
        for (int ct = 0; ct < 8; ++ct) {
            const int j = ct * 16 + m;
            nB[ct] = snwB[j]; mBv[ct] = smB[j];
            imax[ct] = MINV; isum[ct] = 0.f;
        }
        #pragma unroll
        for (int reg = 0; reg < 4; ++reg) {
            const int i = wv * 16 + q * 4 + reg;
            const float na = snwA[i];
            const float ma = smA[i];
            float jmax = MINV, jsum = 0.f;
            #pragma unroll
            for (int ct = 0; ct < 8; ++ct) {
                float v = acc[ct][reg] *
                          __builtin_amdgcn_rcpf(fmaxf(na * nB[ct], EPSF));
                jmax = fmaxf(jmax, mBv[ct] > 0.f ? v : MINV);
                jsum += mBv[ct] > 0.f ? v : 0.f;
                imax[ct] = fmaxf(imax[ct], ma > 0.f ? v : MINV);
                isum[ct] += ma > 0.f ? v : 0.f;
            }
            for (int d = 1; d < 16; d <<= 1) {
                jmax = fmaxf(jmax, __shfl_xor(jmax, d));
                jsum += __shfl_xor(jsum, d);
            }
            if (m == 0) { pJmax[i] = jmax; pJsum[i] = jsum; }
        }
        #pragma unroll
        for (int ct = 0; ct < 8; ++ct) {
            float mx = imax[ct], sm = isum[ct];
            mx = fmaxf(mx, __shfl_xor(mx, 16)); sm += __shfl_xor(sm, 16);
            mx = fmaxf(mx, __shfl_xor(mx, 32)); sm += __shfl_xor(sm, 32);
            if (q == 0) { const int j = ct * 16 + m; pImax[wv * 128 + j] = mx; pIsum[wv * 128 + j] = sm; }
        }
        __syncthreads();

        if (t < 128) {
            const int i = t;
            const float ma = smA[i];
            const float mm = ma * sRed[2];
            const float cnt = ma * sRed[3];
            float* orow = out_p + ((size_t)b * L + i) * C;
            orow[23 + p] = pJmax[i] * mm;
            orow[43 + p] = ma * pJsum[i] / fmaxf(cnt, EPSF);

            const float mb = smB[i];
            float hmax = MINV, hsum = 0.f;
            #pragma unroll
            for (int s = 0; s < 8; ++s) {
                hmax = fmaxf(hmax, pImax[s * 128 + i]);
                hsum += pIsum[s * 128 + i];
            }
            float* hrow = out_h + ((size_t)b * L + i) * C;
            hrow[23 + p] = hmax * mb * sRed[0];
            hrow[43 + p] = mb * hsum / fmaxf(mb * sRed[1], EPSF);
        }
    } else {
        // ==================== side path ====================
        // LDS: BvC [<=128][272] @0 (holes untouched);
        //   scosC@34816 f[8][128]; sa@38912 f[8][112]; sam@42496; sax@46080;
        //   sl@49664 f[112]; pnv@50112.  Pre-phase2 overlay inside sam region:
        //   snB@42496 [128]f, snA@43008 [8]f, cidx@43040 [128]u16.
        //   Post-3b overlay @0: Dscr [8][64][9] f32 (stride 9: conflict-free).
        const int e = bx - P;
        const int side = e >> 4, tile = e & 15;
        const int i0 = tile * TI;
        const float* ctxA = side ? ctx_h : ctx_p;
        const float* ctxB = side ? ctx_p : ctx_h;
        const int* maskA = side ? mask_h : mask_p;
        const int* maskB = side ? mask_p : mask_h;
        float* outBase = out + ((size_t)side * B * L + (size_t)b * L) * C;

        float* scosC = (float*)(smem + 34816);
        float* sa    = (float*)(smem + 38912);
        float* sam   = (float*)(smem + 42496);
        float* sax   = (float*)(smem + 46080);
        float* sl    = (float*)(smem + 49664);
        float* snB   = (float*)(smem + 42496);
        float* snA   = (float*)(smem + 43008);
        u16*  cidx  = (u16*)(smem + 43040);
        int*   pnv   = (int*)(smem + 50112);

        // ---- phase 0: zero scosC; valid-j list (wave 0); sa staging (2-7)
        scosC[t] = 0.f;
        scosC[t + 512] = 0.f;
        if (wv == 0) {
            int m0 = maskB[b * L + ln], m1 = maskB[b * L + 64 + ln];
            unsigned long long b0 = __ballot(m0 > 0);
            unsigned long long b1 = __ballot(m1 > 0);
            unsigned long long pre = (1ull << ln) - 1ull;
            int n0 = __popcll(b0);
            if (m0 > 0) cidx[__popcll(b0 & pre)] = (u16)ln;
            if (m1 > 0) cidx[n0 + __popcll(b1 & pre)] = (u16)(64 + ln);
            if (ln == 0) *pnv = n0 + __popcll(b1);
        } else if (wv >= 2) {
            for (int x = t - 128; x < TI * 128; x += 384) {
                int il = x >> 7, k = x & 127;
                if (k < H) {
                    float mA = (float)maskA[b * L + i0 + il];
                    sa[il * 112 + k] = ctxA[((size_t)b * L + i0 + il) * H + k] * mA;
                }
            }
        }
        __syncthreads();
        const int nv = *pnv;
        const int nct = (nv + 15) >> 4;

        // ---- phase 1: compact bf16 Bv rows from ctx (valid rows => mask 1),
        //      stride 272 B, zero tail; then norms snB/snA; wave1: sl
        {
            for (int c = t; c < nct * 256; c += 512) {
                int jj = c >> 4, cc = c & 15, k0 = cc * 8;
                uint4 o;
                if (jj < nv) {
                    const float* rowp = ctxB + ((size_t)b * L + (int)cidx[jj]) * H;
                    float4 h0 = (k0 <= 96) ? *(const float4*)(rowp + k0) : zero4();
                    float4 h1 = (k0 + 4 <= 96) ? *(const float4*)(rowp + k0 + 4) : zero4();
                    o = pack8(h0, h1);
                } else { o.x = o.y = o.z = o.w = 0u; }
                *(uint4*)(smem + jj * 272 + k0 * 2) = o;
            }
            {   // snB: 4 threads per jj, 25 k each (fp32 from ctx)
                const int jj = t >> 2, quarter = t & 3;
                float acc = 0.f;
                if (jj < nv) {
                    const float* rowp = ctxB + ((size_t)b * L + (int)cidx[jj]) * H;
                    #pragma unroll 5
                    for (int k = quarter * 25; k < quarter * 25 + 25; ++k) {
                        float v = rowp[k];
                        acc += v * v;
                    }
                }
                acc += __shfl_xor(acc, 1);
                acc += __shfl_xor(acc, 2);
                if (quarter == 0) snB[jj] = (jj < nv) ? sqrtf(acc) : 0.f;
            }
            if (t < 32) {    // snA: 4 threads per il from masked sa (LDS)
                const int il = t >> 2, quarter = t & 3;
                float acc = 0.f;
                #pragma unroll 5
                for (int k = quarter * 25; k < quarter * 25 + 25; ++k) {
                    float v = sa[il * 112 + k];
                    acc += v * v;
                }
                acc += __shfl_xor(acc, 1);
                acc += __shfl_xor(acc, 2);
                if (quarter == 0) snA[il] = sqrtf(acc);
            }
            if (wv == 1) {   // sl: reference uses raw row (nv-1) of masked B
                int last = nv - 1; if (last < 0) last = 0;
                const float mLast = (float)maskB[b * L + last];
                const float* lr = ctxB + ((size_t)b * L + last) * H;
                sl[ln] = lr[ln] * mLast;
                if (ln + 64 < H) sl[ln + 64] = lr[ln + 64] * mLast;
            }
        }
        __syncthreads();

        // ---- phase cos: wave wv owns col-tile ct=wv (nct <= 8)
        const int m = ln & 15, q = ln >> 4;
        if (wv < nct) {
            const int il8 = m & 7;
            const float* rowp = ctxA + ((size_t)b * L + i0 + il8) * H;
            const float mA = (m < 8) ? (float)maskA[b * L + i0 + il8] : 0.f;
            f4 acc0 = (f4){0.f, 0.f, 0.f, 0.f};
            #pragma unroll
            for (int ks = 0; ks < 4; ++ks) {
                const int k0 = ks * 32 + q * 8;
                float4 h0 = (k0 <= 96) ? *(const float4*)(rowp + k0) : zero4();
                float4 h1 = (k0 + 4 <= 96) ? *(const float4*)(rowp + k0 + 4) : zero4();
                uint4 o;
                o.x = pack2(h0.x * mA, h0.y * mA);
                o.y = pack2(h0.z * mA, h0.w * mA);
                o.z = pack2(h1.x * mA, h1.y * mA);
                o.w = pack2(h1.z * mA, h1.w * mA);
                sh8 af = __builtin_bit_cast(sh8, o);
                const int ko2 = k0 * 2;
                sh8 bb = *(const sh8*)(smem + (wv * 16 + m) * 272 + ko2);
                acc0 = __builtin_amdgcn_mfma_f32_16x16x32_bf16(af, bb, acc0, 0, 0, 0);
            }
            if (q < 2) {
                #pragma unroll
                for (int reg = 0; reg < 4; ++reg) {
                    const int i = q * 4 + reg;
                    const int jj = wv * 16 + m;
                    scosC[i * 128 + jj] = acc0[reg] *
                        __builtin_amdgcn_rcpf(fmaxf(snA[i] * snB[jj], EPSF));
                }
            }
        }
        __syncthreads();

        // ---- phase 2: butterfly scalars + attentive am/ax; wave wv = row wv
        {
            const int il = wv;
            const int gi = i0 + il;
            const float mA = (float)maskA[b * L + gi];
            float c0 = scosC[il * 128 + ln], c1 = scosC[il * 128 + 64 + ln];
            float scj = c0 + c1;
            float mv0 = (ln < nv) ? c0 : MINV;
            float mv1 = (ln + 64 < nv) ? c1 : MINV;
            float cmx = fmaxf(mv0, mv1);
            for (int d = 1; d < 64; d <<= 1) {
                scj += __shfl_xor(scj, d);
                cmx = fmaxf(cmx, __shfl_xor(cmx, d));
            }
            const float mm = (nv > 0) ? mA : 0.f;
            if (ln == 0) {
                float* orow = outBase + (size_t)gi * C;
                orow[0] = cmx * mm;
                orow[1] = mA * scj / fmaxf(mA * (float)nv, EPSF);
            }
            if (ln < 50) {
                float am0 = 0.f, am1 = 0.f, ax0 = MINV, ax1 = MINV;
                const u32* bp = (const u32*)smem + ln;       // row stride 68 dwords
                const float* cr = scosC + il * 128;
                #pragma unroll 4
                for (int jj = 0; jj < nv; ++jj) {
                    u32 pk = bp[jj * 68];
                    float cj = cr[jj];
                    float v0 = cj * __uint_as_float(pk << 16);
                    float v1 = cj * __uint_as_float(pk & 0xffff0000u);
                    am0 += v0; am1 += v1;
                    ax0 = fmaxf(ax0, v0); ax1 = fmaxf(ax1, v1);
                }
                const float rs = __builtin_amdgcn_rcpf(fmaxf(scj, EPSF));
                sam[il * 112 + 2 * ln] = am0 * rs; sam[il * 112 + 2 * ln + 1] = am1 * rs;
                sax[il * 112 + 2 * ln] = ax0 * mm; sax[il * 112 + 2 * ln + 1] = ax1 * mm;
            }
        }
        __syncthreads();

        // ---- phase 3a: Bcols (products, bf16, stride 136u16) + w2sq stack
        for (int idx = t; idx < 8 * 8 * 17; idx += 512) {
            int kc = (idx % 17) * 8;
            int tmp = idx / 17;                  // il*8 + col
            int il = tmp >> 3, col = tmp & 7;
            const float* sa_il  = sa  + il * 112;
            const float* sam_il = sam + il * 112;
            const float* sax_il = sax + il * 112;
            const float* p1 = (col >= 4) ? (col == 4 ? sl : col == 5 ? sam_il : sax_il)
                                         : sa_il;
            const float* p2 = (col == 0 || col == 4) ? sl :
                              (col == 1 || col == 5) ? sam_il :
                              (col == 2 || col == 6) ? sax_il : sa_il;
            u32 ow[4];
            #pragma unroll
            for (int e2 = 0; e2 < 4; ++e2) {
                int k0 = kc + 2 * e2;
                float f0 = (col < 7 && k0 < H)     ? p1[k0] * p2[k0]         : 0.f;
                float f1 = (col < 7 && k0 + 1 < H) ? p1[k0 + 1] * p2[k0 + 1] : 0.f;
                ow[e2] = pack2(f0, f1);
            }
            uint4 o = {ow[0], ow[1], ow[2], ow[3]};
            *(uint4*)(smem + (tmp * 136 + kc) * 2) = o;
        }
        for (int idx = t; idx < 64 * 17; idx += 512) {
            int kc = (idx % 17) * 8;
            int row = idx / 17;
            u32 ow[4];
            #pragma unroll
            for (int e2 = 0; e2 < 4; ++e2) {
                int k0 = kc + 2 * e2;
                float f0 = 0.f, f1 = 0.f;
                if (row < 60) {
                    const float* wr = (row < 20) ? w0 + row * H :
                                      (row < 40) ? w2 + (row - 20) * H :
                                                   w3 + (row - 40) * H;
                    if (k0 < H)     { float w = wr[k0];     f0 = w * w; }
                    if (k0 + 1 < H) { float w = wr[k0 + 1]; f1 = w * w; }
                } else if (row == 60) {
                    f0 = (k0 < H) ? 1.f : 0.f;
                    f1 = (k0 + 1 < H) ? 1.f : 0.f;
                }
                ow[e2] = pack2(f0, f1);
            }
            uint4 o = {ow[0], ow[1], ow[2], ow[3]};
            *(uint4*)(smem + 17408 + (row * 136 + kc) * 2) = o;
        }
        __syncthreads();

        // ---- phase 3b: D[61x7] = w2sq x Bcols^T per il (wave wv -> il=wv)
        f4 d3[4];
        #pragma unroll
        for (int Mt = 0; Mt < 4; ++Mt) d3[Mt] = (f4){0.f, 0.f, 0.f, 0.f};
        {
            const int cn = m & 7;
            #pragma unroll
            for (int ks = 0; ks < 4; ++ks) {
                const int ko2 = (ks * 32 + q * 8) * 2;
                sh8 bb = *(const sh8*)(smem + ((wv * 8 + cn) * 136) * 2 + ko2);
                #pragma unroll
                for (int Mt = 0; Mt < 4; ++Mt) {
                    sh8 aa = *(const sh8*)(smem + 17408 + ((Mt * 16 + m) * 136) * 2 + ko2);
                    d3[Mt] = __builtin_amdgcn_mfma_f32_16x16x32_bf16(aa, bb, d3[Mt], 0, 0, 0);
                }
            }
        }
        __syncthreads();   // all MFMA reads done before Dscr overwrites

        if (m < 8) {       // Dscr stride 9 dwords: banks (9r+m)%32 -> <=2-way
            #pragma unroll
            for (int Mt = 0; Mt < 4; ++Mt)
                #pragma unroll
                for (int reg = 0; reg < 4; ++reg)
                    ((float*)smem)[wv * 576 + (Mt * 16 + q * 4 + reg) * 9 + m] = d3[Mt][reg];
        }
        __syncthreads();

        // ---- phase 3c: 504 output channels from Dscr
        for (int task = t; task < TI * 63; task += 512) {
            const int il = task / 63, c = task - il * 63;
            int row, dcol, nbcol, chn;
            if (c < 60) {
                const int grp = c / 20;
                row = c; dcol = grp; nbcol = 4 + grp;
                chn = ((grp == 0) ? 3 : (grp == 1) ? 64 : 85) + (c - grp * 20);
            } else {
                const int cc = c - 60;
                row = 60; dcol = cc; nbcol = 4 + cc;
                chn = (cc == 0) ? 2 : (cc == 1) ? 63 : 84;
            }
            const float* Dr = (const float*)smem + il * 576 + row * 9;
            float d = Dr[dcol], na = Dr[3], nb = Dr[nbcol];
            outBase[(size_t)(i0 + il) * C + chn] =
                d / (fmaxf(sqrtf(na), EPSF) * fmaxf(sqrtf(nb), EPSF));
        }
    }
}

// ---------------------------------------------------------------- launch
extern "C" void kernel_launch(void* const* d_in, const int* in_sizes, int n_in,
                              void* d_out, int out_size, void* d_ws, size_t ws_size,
                              hipStream_t stream)
{
    const float* ctx_p = (const float*)d_in[0];
    const int*   mask_p = (const int*)d_in[1];
    const float* ctx_h = (const float*)d_in[2];
    const int*   mask_h = (const int*)d_in[3];
    const float* w0 = (const float*)d_in[4];
    const float* w1 = (const float*)d_in[5];
    const float* w2 = (const float*)d_in[6];
    const float* w3 = (const float*)d_in[7];
    float* out = (float*)d_out;
    (void)d_ws; (void)ws_size;

    k_main<<<dim3(P + 32, B), dim3(512), 0, stream>>>(
        ctx_p, mask_p, ctx_h, mask_h, w0, w1, w2, w3, out);
}